// Round 10
// baseline (31.228 us; speedup 1.0000x reference)
//
#include <hip/hip_runtime.h>
#include <math.h>

// Batched 3x3 polar decomposition — steady-state pipelined, wave-autonomous.
// Each wave owns 512 consecutive matrices = 4 tiles x 128, double-buffered
// LDS, counted s_waitcnt vmcnt (NEVER 0 mid-pipe): next tile's loads and the
// previous tile's stores stay in flight under the current tile's compute.
// vmcnt ledger (in-order retirement):
//   NT(2) L0(6) L1(6) | vmcnt(6) | S0(5) L2(6) | vmcnt(11) | S1(5) L3(6)
//   | vmcnt(11) | S2(5) | vmcnt(5) | S3(5)
// Math: 6 det-scaled Newton (X <- 0.5(zX + sign(det) z^2 Cof X), z=|det|^-1/3,
// no division) + 2 Newton-Schulz polish; 2 matrices/thread in v2f -> packed fp32.
// Stores: coalesced per-instruction line-contiguous -> nontemporal is safe
// (R6: nt on scattered stores = 3.4x write amplification; R7: cached scattered
//  stores = ~64 L2 transactions/instr. Both verified-bad.)

typedef float v2f __attribute__((ext_vector_type(2)));
typedef float v4f __attribute__((ext_vector_type(4)));

#define NEWTON_ITERS 6
#define NS_ITERS 2

__device__ __forceinline__ void polar_pair(
    v2f& x00, v2f& x01, v2f& x02,
    v2f& x10, v2f& x11, v2f& x12,
    v2f& x20, v2f& x21, v2f& x22)
{
    #pragma unroll
    for (int it = 0; it < NEWTON_ITERS; ++it) {
        v2f c00 = x11*x22 - x12*x21;
        v2f c01 = x12*x20 - x10*x22;
        v2f c02 = x10*x21 - x11*x20;
        v2f c10 = x02*x21 - x01*x22;
        v2f c11 = x00*x22 - x02*x20;
        v2f c12 = x01*x20 - x00*x21;
        v2f c20 = x01*x12 - x02*x11;
        v2f c21 = x02*x10 - x00*x12;
        v2f c22 = x00*x11 - x01*x10;

        v2f det = x00*c00 + x01*c01 + x02*c02;

        float d0 = det.x, d1 = det.y;
        float ad0 = fmaxf(fabsf(d0), 1e-30f);
        float ad1 = fmaxf(fabsf(d1), 1e-30f);
        float z0 = __builtin_amdgcn_exp2f(__builtin_amdgcn_logf(ad0) * (-1.0f/3.0f));
        float z1 = __builtin_amdgcn_exp2f(__builtin_amdgcn_logf(ad1) * (-1.0f/3.0f));
        v2f s = {0.5f * z0, 0.5f * z1};
        v2f u = {copysignf(0.5f * z0 * z0, d0), copysignf(0.5f * z1 * z1, d1)};

        x00 = s*x00 + u*c00;  x01 = s*x01 + u*c01;  x02 = s*x02 + u*c02;
        x10 = s*x10 + u*c10;  x11 = s*x11 + u*c11;  x12 = s*x12 + u*c12;
        x20 = s*x20 + u*c20;  x21 = s*x21 + u*c21;  x22 = s*x22 + u*c22;
    }

    #pragma unroll
    for (int it = 0; it < NS_ITERS; ++it) {
        v2f s00 = x00*x00 + x10*x10 + x20*x20;
        v2f s01 = x00*x01 + x10*x11 + x20*x21;
        v2f s02 = x00*x02 + x10*x12 + x20*x22;
        v2f s11 = x01*x01 + x11*x11 + x21*x21;
        v2f s12 = x01*x02 + x11*x12 + x21*x22;
        v2f s22 = x02*x02 + x12*x12 + x22*x22;
        v2f t00 = 1.5f - 0.5f*s00, t01 = -0.5f*s01, t02 = -0.5f*s02;
        v2f t11 = 1.5f - 0.5f*s11, t12 = -0.5f*s12;
        v2f t22 = 1.5f - 0.5f*s22;
        v2f y00 = x00*t00 + x01*t01 + x02*t02;
        v2f y01 = x00*t01 + x01*t11 + x02*t12;
        v2f y02 = x00*t02 + x01*t12 + x02*t22;
        v2f y10 = x10*t00 + x11*t01 + x12*t02;
        v2f y11 = x10*t01 + x11*t11 + x12*t12;
        v2f y12 = x10*t02 + x11*t12 + x12*t22;
        v2f y20 = x20*t00 + x21*t01 + x22*t02;
        v2f y21 = x20*t01 + x21*t11 + x22*t12;
        v2f y22 = x20*t02 + x21*t12 + x22*t22;
        x00=y00; x01=y01; x02=y02;
        x10=y10; x11=y11; x12=y12;
        x20=y20; x21=y21; x22=y22;
    }
}

// stage one 128-matrix tile: 1152 floats = 4x16B + 2x4B per lane (6 vmem ops)
__device__ __forceinline__ void stage_tile(const float* gsrc, float* buf, int lane)
{
    #pragma unroll
    for (int k = 0; k < 4; ++k) {
        __builtin_amdgcn_global_load_lds(
            (const __attribute__((address_space(1))) void*)(gsrc + k * 256 + lane * 4),
            (__attribute__((address_space(3))) void*)(buf + k * 256),
            16, 0, 0);
    }
    #pragma unroll
    for (int k = 0; k < 2; ++k) {
        __builtin_amdgcn_global_load_lds(
            (const __attribute__((address_space(1))) void*)(gsrc + 1024 + k * 64 + lane),
            (__attribute__((address_space(3))) void*)(buf + 1024 + k * 64),
            4, 0, 0);
    }
}

// compute one tile from buf, restage into buf, nt-store coalesced (5 vmem ops)
__device__ __forceinline__ void compute_store_tile(
    float* buf, int lane, float* outBase,
    float m00, float m01, float m02,
    float m10, float m11, float m12,
    float m20, float m21, float m22)
{
    const float* L = buf + lane * 18;
    v2f r00 = {L[0], L[9]},  r01 = {L[1], L[10]}, r02 = {L[2], L[11]};
    v2f r10 = {L[3], L[12]}, r11 = {L[4], L[13]}, r12 = {L[5], L[14]};
    v2f r20 = {L[6], L[15]}, r21 = {L[7], L[16]}, r22 = {L[8], L[17]};

    v2f x00 = m00*r00 + m01*r10 + m02*r20;
    v2f x01 = m00*r01 + m01*r11 + m02*r21;
    v2f x02 = m00*r02 + m01*r12 + m02*r22;
    v2f x10 = m10*r00 + m11*r10 + m12*r20;
    v2f x11 = m10*r01 + m11*r11 + m12*r21;
    v2f x12 = m10*r02 + m11*r12 + m12*r22;
    v2f x20 = m20*r00 + m21*r10 + m22*r20;
    v2f x21 = m20*r01 + m21*r11 + m22*r21;
    v2f x22 = m20*r02 + m21*r12 + m22*r22;

    polar_pair(x00,x01,x02,x10,x11,x12,x20,x21,x22);

    float* S = buf + lane * 18;
    S[0]=x00.x; S[9] =x00.y; S[1]=x01.x; S[10]=x01.y; S[2]=x02.x; S[11]=x02.y;
    S[3]=x10.x; S[12]=x10.y; S[4]=x11.x; S[13]=x11.y; S[5]=x12.x; S[14]=x12.y;
    S[6]=x20.x; S[15]=x20.y; S[7]=x21.x; S[16]=x21.y; S[8]=x22.x; S[17]=x22.y;

    // per-instruction line-contiguous (1 KiB/wave) -> nt safe
    v4f* g4 = (v4f*)outBase;
    const v4f* l4 = (const v4f*)buf;
    #pragma unroll
    for (int k = 0; k < 4; ++k)
        __builtin_nontemporal_store(l4[k * 64 + lane], g4 + k * 64 + lane);
    __builtin_nontemporal_store(((const v2f*)(buf + 1024))[lane],
                                (v2f*)(outBase + 1024) + lane);
}

__global__ __launch_bounds__(256) void polar3x3_ss_kernel(
    const float* __restrict__ rot,   // [n,3,3]
    const float* __restrict__ mat,   // [3,3] broadcast
    float* __restrict__ out,         // [n,3,3] then logdet[n]
    int n)
{
    __shared__ __align__(16) float lds[9216];   // 4 waves * 2 bufs * 1152
    const int t    = threadIdx.x;
    const int lane = t & 63;
    const int w    = t >> 6;
    const long long blockBase = (long long)blockIdx.x * 2048;   // matrices/block
    const long long waveBase  = blockBase + (long long)w * 512; // 4 tiles x 128
    float* buf0 = lds + w * 2304;
    float* buf1 = buf0 + 1152;

    const float m00 = mat[0], m01 = mat[1], m02 = mat[2];
    const float m10 = mat[3], m11 = mat[4], m12 = mat[5];
    const float m20 = mat[6], m21 = mat[7], m22 = mat[8];

    const bool full = (blockBase + 2048 <= (long long)n);

    if (full) {
        // logdet zeros for this wave's 512 matrices: 2 v4f per lane, contiguous
        v4f* ld4 = (v4f*)(out + (long long)n * 9 + waveBase);
        __builtin_nontemporal_store(v4f{0.f,0.f,0.f,0.f}, ld4 + lane);
        __builtin_nontemporal_store(v4f{0.f,0.f,0.f,0.f}, ld4 + 64 + lane);

        stage_tile(rot + waveBase * 9,           buf0, lane);  // L0
        stage_tile(rot + (waveBase + 128) * 9,   buf1, lane);  // L1

        // [NT2 L0:6 L1:6]=14 ; need NT+L0 retired -> vmcnt(6)
        asm volatile("s_waitcnt vmcnt(6)" ::: "memory");
        compute_store_tile(buf0, lane, out + waveBase * 9,
                           m00,m01,m02,m10,m11,m12,m20,m21,m22);   // S0
        stage_tile(rot + (waveBase + 256) * 9, buf0, lane);        // L2

        // [L1:6 S0:5 L2:6]=17 ; need L1 retired -> vmcnt(11)
        asm volatile("s_waitcnt vmcnt(11)" ::: "memory");
        compute_store_tile(buf1, lane, out + (waveBase + 128) * 9,
                           m00,m01,m02,m10,m11,m12,m20,m21,m22);   // S1
        stage_tile(rot + (waveBase + 384) * 9, buf1, lane);        // L3

        // [S0:5 L2:6 S1:5 L3:6]=22 ; need S0+L2 retired -> vmcnt(11)
        asm volatile("s_waitcnt vmcnt(11)" ::: "memory");
        compute_store_tile(buf0, lane, out + (waveBase + 256) * 9,
                           m00,m01,m02,m10,m11,m12,m20,m21,m22);   // S2

        // [S1:5 L3:6 S2:5]=16 ; need S1+L3 retired -> vmcnt(5)
        asm volatile("s_waitcnt vmcnt(5)" ::: "memory");
        compute_store_tile(buf1, lane, out + (waveBase + 384) * 9,
                           m00,m01,m02,m10,m11,m12,m20,m21,m22);   // S3
    } else {
        // tail: guarded scalar path, 4 tiles of 128
        #pragma unroll 1
        for (int tile = 0; tile < 4; ++tile) {
            long long tileBase = waveBase + (long long)tile * 128;
            v2f r00,r01,r02,r10,r11,r12,r20,r21,r22;
            #pragma unroll
            for (int q = 0; q < 2; ++q) {
                long long mi = tileBase + 2 * lane + q;
                if (mi < (long long)n) {
                    const float* r = rot + mi * 9;
                    r00[q]=r[0]; r01[q]=r[1]; r02[q]=r[2];
                    r10[q]=r[3]; r11[q]=r[4]; r12[q]=r[5];
                    r20[q]=r[6]; r21[q]=r[7]; r22[q]=r[8];
                } else {
                    r00[q]=1.f; r01[q]=0.f; r02[q]=0.f;
                    r10[q]=0.f; r11[q]=1.f; r12[q]=0.f;
                    r20[q]=0.f; r21[q]=0.f; r22[q]=1.f;
                }
            }
            v2f x00 = m00*r00 + m01*r10 + m02*r20;
            v2f x01 = m00*r01 + m01*r11 + m02*r21;
            v2f x02 = m00*r02 + m01*r12 + m02*r22;
            v2f x10 = m10*r00 + m11*r10 + m12*r20;
            v2f x11 = m10*r01 + m11*r11 + m12*r21;
            v2f x12 = m10*r02 + m11*r12 + m12*r22;
            v2f x20 = m20*r00 + m21*r10 + m22*r20;
            v2f x21 = m20*r01 + m21*r11 + m22*r21;
            v2f x22 = m20*r02 + m21*r12 + m22*r22;
            polar_pair(x00,x01,x02,x10,x11,x12,x20,x21,x22);
            #pragma unroll
            for (int q = 0; q < 2; ++q) {
                long long mi = tileBase + 2 * lane + q;
                if (mi < (long long)n) {
                    float* o = out + mi * 9;
                    o[0]=x00[q]; o[1]=x01[q]; o[2]=x02[q];
                    o[3]=x10[q]; o[4]=x11[q]; o[5]=x12[q];
                    o[6]=x20[q]; o[7]=x21[q]; o[8]=x22[q];
                    out[(long long)n * 9 + mi] = 0.0f;
                }
            }
        }
    }
}

extern "C" void kernel_launch(void* const* d_in, const int* in_sizes, int n_in,
                              void* d_out, int out_size, void* d_ws, size_t ws_size,
                              hipStream_t stream) {
    const float* rot = (const float*)d_in[0];
    const float* mat = (const float*)d_in[1];
    float* out = (float*)d_out;

    int n = in_sizes[0] / 9;
    int block = 256;                   // 4 waves; each wave owns 512 matrices
    int grid = (n + 2047) / 2048;      // 2048 matrices per block
    polar3x3_ss_kernel<<<grid, block, 0, stream>>>(rot, mat, out, n);
}

// Round 11
// 29.597 us; speedup vs baseline: 1.0551x; 1.0551x over previous
//
#include <hip/hip_runtime.h>
#include <math.h>

// Batched 3x3 polar decomposition, wave-autonomous (best structure, R5):
//  - each wave stages its own 128 matrices global->LDS via global_load_lds
//    (linear dest, 4x16B + 2x4B per lane), NO __syncthreads anywhere
//  - logdet NT fill issued BEFORE the vmcnt wait (independent work)
//  - 2 matrices/thread packed into v2f -> v_pk_fma_f32
//  - 6 det-scaled Newton (X <- 0.5(zX + sign(det) z^2 Cof X), z=|det|^-1/3,
//    division-free) + 2 Newton-Schulz polish
//  - output restaged through the wave's LDS region -> coalesced nt v4f stores
//    (R6: nt on scattered stores = 3.4x write amplification;
//     R7: cached scattered stores = ~64 L2 transactions/instr)
// Roofline note: 162 MB combined R+W per call; 29.7 us = 5.45 TB/s mixed
// traffic ~ 87% of the 6.3 TB/s copy ceiling. Five structures (R2,R5,R8,R9,
// R10) all converge to 30+-2 us -> memory-bound floor, not structure-bound.

typedef float v2f __attribute__((ext_vector_type(2)));
typedef float v4f __attribute__((ext_vector_type(4)));

#define NEWTON_ITERS 6
#define NS_ITERS 2

__device__ __forceinline__ void polar_pair(
    v2f& x00, v2f& x01, v2f& x02,
    v2f& x10, v2f& x11, v2f& x12,
    v2f& x20, v2f& x21, v2f& x22)
{
    #pragma unroll
    for (int it = 0; it < NEWTON_ITERS; ++it) {
        v2f c00 = x11*x22 - x12*x21;
        v2f c01 = x12*x20 - x10*x22;
        v2f c02 = x10*x21 - x11*x20;
        v2f c10 = x02*x21 - x01*x22;
        v2f c11 = x00*x22 - x02*x20;
        v2f c12 = x01*x20 - x00*x21;
        v2f c20 = x01*x12 - x02*x11;
        v2f c21 = x02*x10 - x00*x12;
        v2f c22 = x00*x11 - x01*x10;

        v2f det = x00*c00 + x01*c01 + x02*c02;

        float d0 = det.x, d1 = det.y;
        float ad0 = fmaxf(fabsf(d0), 1e-30f);
        float ad1 = fmaxf(fabsf(d1), 1e-30f);
        float z0 = __builtin_amdgcn_exp2f(__builtin_amdgcn_logf(ad0) * (-1.0f/3.0f));
        float z1 = __builtin_amdgcn_exp2f(__builtin_amdgcn_logf(ad1) * (-1.0f/3.0f));
        v2f s = {0.5f * z0, 0.5f * z1};
        v2f u = {copysignf(0.5f * z0 * z0, d0), copysignf(0.5f * z1 * z1, d1)};

        x00 = s*x00 + u*c00;  x01 = s*x01 + u*c01;  x02 = s*x02 + u*c02;
        x10 = s*x10 + u*c10;  x11 = s*x11 + u*c11;  x12 = s*x12 + u*c12;
        x20 = s*x20 + u*c20;  x21 = s*x21 + u*c21;  x22 = s*x22 + u*c22;
    }

    #pragma unroll
    for (int it = 0; it < NS_ITERS; ++it) {
        v2f s00 = x00*x00 + x10*x10 + x20*x20;
        v2f s01 = x00*x01 + x10*x11 + x20*x21;
        v2f s02 = x00*x02 + x10*x12 + x20*x22;
        v2f s11 = x01*x01 + x11*x11 + x21*x21;
        v2f s12 = x01*x02 + x11*x12 + x21*x22;
        v2f s22 = x02*x02 + x12*x12 + x22*x22;
        v2f t00 = 1.5f - 0.5f*s00, t01 = -0.5f*s01, t02 = -0.5f*s02;
        v2f t11 = 1.5f - 0.5f*s11, t12 = -0.5f*s12;
        v2f t22 = 1.5f - 0.5f*s22;
        v2f y00 = x00*t00 + x01*t01 + x02*t02;
        v2f y01 = x00*t01 + x01*t11 + x02*t12;
        v2f y02 = x00*t02 + x01*t12 + x02*t22;
        v2f y10 = x10*t00 + x11*t01 + x12*t02;
        v2f y11 = x10*t01 + x11*t11 + x12*t12;
        v2f y12 = x10*t02 + x11*t12 + x12*t22;
        v2f y20 = x20*t00 + x21*t01 + x22*t02;
        v2f y21 = x20*t01 + x21*t11 + x22*t12;
        v2f y22 = x20*t02 + x21*t12 + x22*t22;
        x00=y00; x01=y01; x02=y02;
        x10=y10; x11=y11; x12=y12;
        x20=y20; x21=y21; x22=y22;
    }
}

__global__ __launch_bounds__(256) void polar3x3_wave_kernel(
    const float* __restrict__ rot,   // [n,3,3]
    const float* __restrict__ mat,   // [3,3] broadcast
    float* __restrict__ out,         // [n,3,3] then logdet[n]
    int n)
{
    __shared__ __align__(16) float lds[4608];   // 4 waves * 1152 floats
    const int t    = threadIdx.x;
    const int lane = t & 63;
    const int w    = t >> 6;
    const long long blockBase = (long long)blockIdx.x * 512;  // matrices
    const long long waveBase  = blockBase + (long long)w * 128;
    float* wlds = lds + w * 1152;

    // uniform parameter (scalar loads, overlap with staging)
    const float m00 = mat[0], m01 = mat[1], m02 = mat[2];
    const float m10 = mat[3], m11 = mat[4], m12 = mat[5];
    const float m20 = mat[6], m21 = mat[7], m22 = mat[8];

    const bool full = (blockBase + 512 <= (long long)n);

    v2f r00, r01, r02, r10, r11, r12, r20, r21, r22;

    if (full) {
        // ---- wave-local staging: 1152 floats, linear, no barrier ----
        const float* gsrc = rot + waveBase * 9;
        #pragma unroll
        for (int k = 0; k < 4; ++k) {
            __builtin_amdgcn_global_load_lds(
                (const __attribute__((address_space(1))) void*)(gsrc + k * 256 + lane * 4),
                (__attribute__((address_space(3))) void*)(wlds + k * 256),
                16, 0, 0);
        }
        #pragma unroll
        for (int k = 0; k < 2; ++k) {
            __builtin_amdgcn_global_load_lds(
                (const __attribute__((address_space(1))) void*)(gsrc + 1024 + k * 64 + lane),
                (__attribute__((address_space(3))) void*)(wlds + 1024 + k * 64),
                4, 0, 0);
        }

        // logdet zeros: independent of staging -> issue before the wait.
        // per-instruction line-contiguous (512B/wave) -> nt safe.
        v2f* ld2 = (v2f*)(out + (long long)n * 9 + waveBase + 2 * lane);
        __builtin_nontemporal_store(v2f{0.f, 0.f}, ld2);

        asm volatile("s_waitcnt vmcnt(0)" ::: "memory");

        const float* L = wlds + lane * 18;   // this lane's 2 matrices
        r00 = v2f{L[0], L[9]};  r01 = v2f{L[1], L[10]}; r02 = v2f{L[2], L[11]};
        r10 = v2f{L[3], L[12]}; r11 = v2f{L[4], L[13]}; r12 = v2f{L[5], L[14]};
        r20 = v2f{L[6], L[15]}; r21 = v2f{L[7], L[16]}; r22 = v2f{L[8], L[17]};
    } else {
        // tail block: direct guarded scalar loads, identity padding
        #pragma unroll
        for (int q = 0; q < 2; ++q) {
            long long mi = waveBase + 2 * lane + q;
            if (mi < (long long)n) {
                const float* r = rot + mi * 9;
                r00[q]=r[0]; r01[q]=r[1]; r02[q]=r[2];
                r10[q]=r[3]; r11[q]=r[4]; r12[q]=r[5];
                r20[q]=r[6]; r21[q]=r[7]; r22[q]=r[8];
            } else {
                r00[q]=1.f; r01[q]=0.f; r02[q]=0.f;
                r10[q]=0.f; r11[q]=1.f; r12[q]=0.f;
                r20[q]=0.f; r21[q]=0.f; r22[q]=1.f;
            }
        }
    }

    // X = mat @ rot
    v2f x00 = m00*r00 + m01*r10 + m02*r20;
    v2f x01 = m00*r01 + m01*r11 + m02*r21;
    v2f x02 = m00*r02 + m01*r12 + m02*r22;
    v2f x10 = m10*r00 + m11*r10 + m12*r20;
    v2f x11 = m10*r01 + m11*r11 + m12*r21;
    v2f x12 = m10*r02 + m11*r12 + m12*r22;
    v2f x20 = m20*r00 + m21*r10 + m22*r20;
    v2f x21 = m20*r01 + m21*r11 + m22*r21;
    v2f x22 = m20*r02 + m21*r12 + m22*r22;

    polar_pair(x00,x01,x02,x10,x11,x12,x20,x21,x22);

    if (full) {
        // ---- restage results in the wave's own region (in-order DS pipe,
        // wave-local RAW: compiler inserts lgkmcnt) -> coalesced nt stores ----
        float* S = wlds + lane * 18;
        S[0]=x00.x; S[9] =x00.y; S[1]=x01.x; S[10]=x01.y; S[2]=x02.x; S[11]=x02.y;
        S[3]=x10.x; S[12]=x10.y; S[4]=x11.x; S[13]=x11.y; S[5]=x12.x; S[14]=x12.y;
        S[6]=x20.x; S[15]=x20.y; S[7]=x21.x; S[16]=x21.y; S[8]=x22.x; S[17]=x22.y;

        v4f* gdst4 = (v4f*)(out + waveBase * 9);
        const v4f* l4 = (const v4f*)wlds;
        #pragma unroll
        for (int k = 0; k < 4; ++k)
            __builtin_nontemporal_store(l4[k * 64 + lane], gdst4 + k * 64 + lane);
        v2f* gdst2 = (v2f*)(out + waveBase * 9 + 1024);
        const v2f* l2 = (const v2f*)(wlds + 1024);
        __builtin_nontemporal_store(l2[lane], gdst2 + lane);
    } else {
        #pragma unroll
        for (int q = 0; q < 2; ++q) {
            long long mi = waveBase + 2 * lane + q;
            if (mi < (long long)n) {
                float* o = out + mi * 9;
                o[0]=x00[q]; o[1]=x01[q]; o[2]=x02[q];
                o[3]=x10[q]; o[4]=x11[q]; o[5]=x12[q];
                o[6]=x20[q]; o[7]=x21[q]; o[8]=x22[q];
                out[(long long)n * 9 + mi] = 0.0f;
            }
        }
    }
}

extern "C" void kernel_launch(void* const* d_in, const int* in_sizes, int n_in,
                              void* d_out, int out_size, void* d_ws, size_t ws_size,
                              hipStream_t stream) {
    const float* rot = (const float*)d_in[0];
    const float* mat = (const float*)d_in[1];
    float* out = (float*)d_out;

    int n = in_sizes[0] / 9;
    int block = 256;
    int grid = (n + 511) / 512;   // 512 matrices per block, 2 per thread
    polar3x3_wave_kernel<<<grid, block, 0, stream>>>(rot, mat, out, n);
}